// Round 1
// baseline (489.665 us; speedup 1.0000x reference)
//
#include <hip/hip_runtime.h>

#define BB 64
#define CC 8
#define NN 2048
#define TT 64
#define NSPLIT 4
#define NCHUNK (NN / NSPLIT)   // 512
#define NGROUP 2
#define GB (BB / NGROUP)       // 32 batches per group (128 MiB of x -> L3-resident)

typedef float f4_nt __attribute__((ext_vector_type(4)));  // native vec for nontemporal builtins

// ---------------------------------------------------------------------------
// Pass 1 (per group): kp[bc][sp][t] = sum_{i in chunk sp} alpha[i] * x[bc,i,t]
// grid = GB*CC*NSPLIT = 1024 blocks x 256 threads.
// x/kp pointers are pre-offset to the group's base, so bc is group-local.
// ---------------------------------------------------------------------------
__global__ __launch_bounds__(256) void k_partial(const float* __restrict__ x,
                                                 const float* __restrict__ alpha,
                                                 float* __restrict__ kp) {
    const int bc  = blockIdx.x >> 2;    // group-local b*C + c
    const int sp  = blockIdx.x & 3;     // N-split 0..3
    const int tid = threadIdx.x;
    const int t4  = tid & 15;           // float4 index within T
    const int ig  = tid >> 4;           // i-group 0..15

    __shared__ float aS[NCHUNK];        // 2 KiB: alpha chunk staged once
    const int i0 = sp * NCHUNK;
    for (int j = tid; j < NCHUNK; j += 256) aS[j] = alpha[i0 + j];
    __syncthreads();

    const float4* xp = (const float4*)(x + ((size_t)bc * NN + i0) * TT);
    float4 acc = make_float4(0.f, 0.f, 0.f, 0.f);
    // 32 iterations; unroll 8 -> 8 independent 1 KiB wave-loads in flight
    #pragma unroll 8
    for (int i = ig; i < NCHUNK; i += 16) {
        const float  a = aS[i];
        const float4 v = xp[i * 16 + t4];
        acc.x = fmaf(a, v.x, acc.x);
        acc.y = fmaf(a, v.y, acc.y);
        acc.z = fmaf(a, v.z, acc.z);
        acc.w = fmaf(a, v.w, acc.w);
    }

    __shared__ float4 part[16][16];     // [ig][t4]; 2-way bank alias = free
    part[ig][t4] = acc;
    __syncthreads();
    for (int s = 8; s > 0; s >>= 1) {
        if (ig < s) {
            const float4 o = part[ig + s][t4];
            acc.x += o.x; acc.y += o.y; acc.z += o.z; acc.w += o.w;
            part[ig][t4] = acc;
        }
        __syncthreads();
    }
    if (ig == 0)
        ((float4*)(kp + ((size_t)bc * NSPLIT + sp) * TT))[t4] = acc;
}

// ---------------------------------------------------------------------------
// Pass 2 (per group): per batch b — sum split partials -> k[8][64]; m = Wc*k;
// scores = k . m ; softmax over d -> att[b][8][8].
// grid = GB blocks x 256 threads. Wc staged TRANSPOSED (+pad).
// ---------------------------------------------------------------------------
__global__ __launch_bounds__(256) void att_kernel(const float* __restrict__ kp,
                                                  const float* __restrict__ Wc,
                                                  float* __restrict__ att) {
    const int b   = blockIdx.x;         // group-local batch
    const int tid = threadIdx.x;

    __shared__ float wT[TT][TT + 1];    // wT[s][t] = Wc[t][s]
    __shared__ float kS[CC][TT + 1];
    __shared__ float mS[CC][TT + 1];

    // coalesced float4 load of Wc, scattered transpose into padded LDS
    for (int idx = tid; idx < TT * TT / 4; idx += 256) {
        const float4 w = ((const float4*)Wc)[idx];
        const int t = idx >> 4;          // row of Wc
        const int s = (idx & 15) * 4;    // col of Wc
        wT[s + 0][t] = w.x;
        wT[s + 1][t] = w.y;
        wT[s + 2][t] = w.z;
        wT[s + 3][t] = w.w;
    }
    // sum the NSPLIT partials -> k
    for (int idx = tid; idx < CC * TT; idx += 256) {
        const int c = idx >> 6, t = idx & 63;
        float s = 0.f;
        #pragma unroll
        for (int sp = 0; sp < NSPLIT; ++sp)
            s += kp[(((size_t)b * CC + c) * NSPLIT + sp) * TT + t];
        kS[c][t] = s;
    }
    __syncthreads();

    // m[d][t] = sum_s Wc[t][s] * k[d][s] = sum_s wT[s][t] * kS[d][s]
    for (int idx = tid; idx < CC * TT; idx += 256) {
        const int d = idx >> 6, t = idx & 63;
        float acc = 0.f;
        #pragma unroll 8
        for (int s = 0; s < TT; ++s)
            acc = fmaf(wT[s][t], kS[d][s], acc);   // wT: 2-way alias; kS: broadcast
        mS[d][t] = acc;
    }
    __syncthreads();

    // scores[c][d] = sum_t k[c][t]*m[d][t]; softmax over d (8-lane groups)
    if (tid < 64) {
        const int c = tid >> 3, d = tid & 7;
        float sc = 0.f;
        #pragma unroll 8
        for (int t = 0; t < TT; ++t)
            sc = fmaf(kS[c][t], mS[d][t], sc);
        float mx = sc;
        for (int off = 1; off < 8; off <<= 1)
            mx = fmaxf(mx, __shfl_xor(mx, off, 8));
        const float e = __expf(sc - mx);
        float sum = e;
        for (int off = 1; off < 8; off <<= 1)
            sum += __shfl_xor(sum, off, 8);
        att[(size_t)b * CC * CC + tid] = e / sum;
    }
}

// ---------------------------------------------------------------------------
// Pass 3 (per group): out[b,c,n,t] = sum_i att[b,c,i] * x[b,i,n,t]
// grid = GB*(NN/16) = 4096 blocks x 256 threads.
// Block order REVERSED: the group's x slice was just streamed by pass 1, so
// the highest addresses are the hottest L3 lines — consume those first.
// This also makes the schedule robust to out-stores write-allocating: they
// then evict only already-consumed x lines.
// ---------------------------------------------------------------------------
__global__ __launch_bounds__(256) void agg_kernel(const float* __restrict__ x,
                                                  const float* __restrict__ att,
                                                  float* __restrict__ out) {
    const int nblk  = GB * (NN / 16);
    const int bid   = (nblk - 1) - (int)blockIdx.x;   // reversed stream order
    const int b     = bid >> 7;          // group-local batch
    const int ntile = bid & 127;
    const int tid   = threadIdx.x;

    __shared__ float attS[CC * CC];
    if (tid < CC * CC) attS[tid] = att[(size_t)b * CC * CC + tid];
    __syncthreads();

    const int n  = ntile * 16 + (tid >> 4);
    const int t4 = tid & 15;
    const size_t base = ((size_t)b * CC * NN + n) * TT + t4 * 4;

    float4 v[CC];
    #pragma unroll
    for (int i = 0; i < CC; ++i)
        v[i] = *(const float4*)(x + base + (size_t)i * NN * TT);

    float4 acc[CC];
    #pragma unroll
    for (int c = 0; c < CC; ++c) acc[c] = make_float4(0.f, 0.f, 0.f, 0.f);
    #pragma unroll
    for (int i = 0; i < CC; ++i) {
        #pragma unroll
        for (int c = 0; c < CC; ++c) {
            const float a = attS[c * CC + i];
            acc[c].x = fmaf(a, v[i].x, acc[c].x);
            acc[c].y = fmaf(a, v[i].y, acc[c].y);
            acc[c].z = fmaf(a, v[i].z, acc[c].z);
            acc[c].w = fmaf(a, v[i].w, acc[c].w);
        }
    }
    #pragma unroll
    for (int c = 0; c < CC; ++c) {
        f4_nt val = { acc[c].x, acc[c].y, acc[c].z, acc[c].w };
        __builtin_nontemporal_store(val, (f4_nt*)(out + base + (size_t)c * NN * TT));
    }
}

extern "C" void kernel_launch(void* const* d_in, const int* in_sizes, int n_in,
                              void* d_out, int out_size, void* d_ws, size_t ws_size,
                              hipStream_t stream) {
    const float* x     = (const float*)d_in[0];   // [B,C,N,T] fp32
    const float* Wc    = (const float*)d_in[1];   // [T,T]
    const float* alpha = (const float*)d_in[2];   // [N]
    float* out = (float*)d_out;

    float* kpws  = (float*)d_ws;                         // [B*C][NSPLIT][T] = 512 KiB
    float* attws = kpws + (size_t)BB * CC * NSPLIT * TT; // [B][C][C] = 16 KiB

    const size_t xgrp = (size_t)GB * CC * NN * TT;       // 128 MiB of x per group
    const size_t kgrp = (size_t)GB * CC * NSPLIT * TT;
    const size_t agrp = (size_t)GB * CC * CC;

    // Per-group pipeline: agg(g) reads the x slice pass 1 just streamed,
    // while it is guaranteed L3-resident (128 MiB << 256 MiB Infinity Cache).
    for (int g = 0; g < NGROUP; ++g) {
        k_partial <<<GB * CC * NSPLIT, 256, 0, stream>>>(x + g * xgrp, alpha, kpws + g * kgrp);
        att_kernel<<<GB,               256, 0, stream>>>(kpws + g * kgrp, Wc, attws + g * agrp);
        agg_kernel<<<GB * (NN / 16),   256, 0, stream>>>(x + g * xgrp, attws + g * agrp, out + g * xgrp);
    }
}

// Round 2
// 488.527 us; speedup vs baseline: 1.0023x; 1.0023x over previous
//
#include <hip/hip_runtime.h>

#define BB 64
#define CC 8
#define NN 2048
#define TT 64
#define NSPLIT 4
#define NCHUNK (NN / NSPLIT)   // 512

typedef float f4_nt __attribute__((ext_vector_type(4)));  // native vec for nontemporal builtins

// ---------------------------------------------------------------------------
// Pass 1: kp[bc][sp][t] = sum_{i in chunk sp} alpha[i] * x[bc,i,t]
// grid = BB*CC*NSPLIT = 2048 blocks x 256 threads (32 waves/CU for MLP).
// Normal (caching) loads: this pass is what warms L3 with x for pass 2.
// ---------------------------------------------------------------------------
__global__ __launch_bounds__(256) void k_partial(const float* __restrict__ x,
                                                 const float* __restrict__ alpha,
                                                 float* __restrict__ kp) {
    const int bc  = blockIdx.x >> 2;    // 0..511  (b*C + c)
    const int sp  = blockIdx.x & 3;     // N-split 0..3
    const int tid = threadIdx.x;
    const int t4  = tid & 15;           // float4 index within T
    const int ig  = tid >> 4;           // i-group 0..15

    __shared__ float aS[NCHUNK];        // 2 KiB: alpha chunk staged once
    const int i0 = sp * NCHUNK;
    for (int j = tid; j < NCHUNK; j += 256) aS[j] = alpha[i0 + j];
    __syncthreads();

    const float4* xp = (const float4*)(x + ((size_t)bc * NN + i0) * TT);
    float4 acc = make_float4(0.f, 0.f, 0.f, 0.f);
    // 32 iterations; unroll 8 -> 8 independent 1 KiB wave-loads in flight
    #pragma unroll 8
    for (int i = ig; i < NCHUNK; i += 16) {
        const float  a = aS[i];
        const float4 v = xp[i * 16 + t4];
        acc.x = fmaf(a, v.x, acc.x);
        acc.y = fmaf(a, v.y, acc.y);
        acc.z = fmaf(a, v.z, acc.z);
        acc.w = fmaf(a, v.w, acc.w);
    }

    __shared__ float4 part[16][16];     // [ig][t4]; 2-way bank alias = free
    part[ig][t4] = acc;
    __syncthreads();
    for (int s = 8; s > 0; s >>= 1) {
        if (ig < s) {
            const float4 o = part[ig + s][t4];
            acc.x += o.x; acc.y += o.y; acc.z += o.z; acc.w += o.w;
            part[ig][t4] = acc;
        }
        __syncthreads();
    }
    if (ig == 0)
        ((float4*)(kp + ((size_t)bc * NSPLIT + sp) * TT))[t4] = acc;
}

// ---------------------------------------------------------------------------
// Pass 2 (fused): per block — recompute att[b][8][8] from kp (cheap, L2-hot
// broadcast reads), then out[b,c,n,t] = sum_i att[b,c,i] * x[b,i,n,t].
// grid = BB*(NN/16) = 8192 blocks x 256 threads.
// The 8 x-tile loads are issued FIRST so the att prologue (LDS staging,
// m = Wc-weighted k, scores, softmax) hides under their HBM/L3 latency.
// Stores are nontemporal so out-writes don't evict x from L3.
// ---------------------------------------------------------------------------
__global__ __launch_bounds__(256) void agg_fused(const float* __restrict__ x,
                                                 const float* __restrict__ Wc,
                                                 const float* __restrict__ kp,
                                                 float* __restrict__ out) {
    const int nblk  = BB * (NN / 16);
    const int bid   = (nblk - 1) - (int)blockIdx.x;   // reversed stream order
    const int b     = bid >> 7;
    const int ntile = bid & 127;
    const int tid   = threadIdx.x;

    // --- issue the x-tile loads immediately (independent of att) ---
    const int n  = ntile * 16 + (tid >> 4);
    const int t4 = tid & 15;
    const size_t base = ((size_t)b * CC * NN + n) * TT + t4 * 4;
    float4 v[CC];
    #pragma unroll
    for (int i = 0; i < CC; ++i)
        v[i] = *(const float4*)(x + base + (size_t)i * NN * TT);

    // --- att prologue (overlaps with the loads above) ---
    __shared__ float wT[TT][TT + 1];    // wT[s][t] = Wc[t][s] (padded)
    __shared__ float kS[CC][TT + 1];
    __shared__ float mS[CC][TT + 1];
    __shared__ float attS[CC * CC];

    // coalesced float4 load of Wc, scattered transpose into padded LDS
    for (int idx = tid; idx < TT * TT / 4; idx += 256) {
        const float4 w = ((const float4*)Wc)[idx];
        const int t = idx >> 4;          // row of Wc
        const int s = (idx & 15) * 4;    // col of Wc
        wT[s + 0][t] = w.x;
        wT[s + 1][t] = w.y;
        wT[s + 2][t] = w.z;
        wT[s + 3][t] = w.w;
    }
    // sum the NSPLIT partials -> k (kp is 512 KiB total: L2/L3-hot broadcast)
    for (int idx = tid; idx < CC * TT; idx += 256) {
        const int c = idx >> 6, t = idx & 63;
        float s = 0.f;
        #pragma unroll
        for (int sp = 0; sp < NSPLIT; ++sp)
            s += kp[(((size_t)b * CC + c) * NSPLIT + sp) * TT + t];
        kS[c][t] = s;
    }
    __syncthreads();

    // m[d][t] = sum_s Wc[t][s] * k[d][s] = sum_s wT[s][t] * kS[d][s]
    for (int idx = tid; idx < CC * TT; idx += 256) {
        const int d = idx >> 6, t = idx & 63;
        float acc = 0.f;
        #pragma unroll 8
        for (int s = 0; s < TT; ++s)
            acc = fmaf(wT[s][t], kS[d][s], acc);   // wT: 2-way alias; kS: broadcast
        mS[d][t] = acc;
    }
    __syncthreads();

    // scores[c][d] = sum_t k[c][t]*m[d][t]; softmax over d (8-lane groups)
    if (tid < 64) {
        const int c = tid >> 3, d = tid & 7;
        float sc = 0.f;
        #pragma unroll 8
        for (int t = 0; t < TT; ++t)
            sc = fmaf(kS[c][t], mS[d][t], sc);
        float mx = sc;
        for (int off = 1; off < 8; off <<= 1)
            mx = fmaxf(mx, __shfl_xor(mx, off, 8));
        const float e = __expf(sc - mx);
        float sum = e;
        for (int off = 1; off < 8; off <<= 1)
            sum += __shfl_xor(sum, off, 8);
        attS[tid] = e / sum;
    }
    __syncthreads();

    // --- aggregate: acc[c] += att[c][i] * v[i] ---
    float4 acc[CC];
    #pragma unroll
    for (int c = 0; c < CC; ++c) acc[c] = make_float4(0.f, 0.f, 0.f, 0.f);
    #pragma unroll
    for (int i = 0; i < CC; ++i) {
        #pragma unroll
        for (int c = 0; c < CC; ++c) {
            const float a = attS[c * CC + i];
            acc[c].x = fmaf(a, v[i].x, acc[c].x);
            acc[c].y = fmaf(a, v[i].y, acc[c].y);
            acc[c].z = fmaf(a, v[i].z, acc[c].z);
            acc[c].w = fmaf(a, v[i].w, acc[c].w);
        }
    }
    #pragma unroll
    for (int c = 0; c < CC; ++c) {
        f4_nt val = { acc[c].x, acc[c].y, acc[c].z, acc[c].w };
        __builtin_nontemporal_store(val, (f4_nt*)(out + base + (size_t)c * NN * TT));
    }
}

extern "C" void kernel_launch(void* const* d_in, const int* in_sizes, int n_in,
                              void* d_out, int out_size, void* d_ws, size_t ws_size,
                              hipStream_t stream) {
    const float* x     = (const float*)d_in[0];   // [B,C,N,T] fp32
    const float* Wc    = (const float*)d_in[1];   // [T,T]
    const float* alpha = (const float*)d_in[2];   // [N]
    float* out = (float*)d_out;

    float* kpws = (float*)d_ws;                   // [B*C][NSPLIT][T] = 512 KiB

    k_partial<<<BB * CC * NSPLIT, 256, 0, stream>>>(x, alpha, kpws);
    agg_fused<<<BB * (NN / 16),   256, 0, stream>>>(x, Wc, kpws, out);
}